// Round 10
// baseline (163.269 us; speedup 1.0000x reference)
//
#include <hip/hip_runtime.h>
#include <stdint.h>

#define NNODES 1024
#define NGRAPH 128
#define TOPK   16384
#define EQCAP  4096

typedef float vfloat4 __attribute__((ext_vector_type(4)));

// Order-preserving monotone map fp32 -> u32 (larger float => larger key).
__device__ __forceinline__ uint32_t fkey(float x) {
    uint32_t u = __float_as_uint(x);
    return (u & 0x80000000u) ? ~u : (u | 0x80000000u);
}

// ---------------------------------------------------------------------------
// Fused selection kernel, one 1024-thread block per graph. R5-validated
// structure verbatim (LDS bitonic sort + 33-iter key-space binary search with
// per-row interval tracking), plus cntHi tracking (validated R6/R7/R9) so the
// final exact-count pass is dropped. Emits T, R, and the tie list.
// ---------------------------------------------------------------------------
__global__ __launch_bounds__(NNODES)
void select_kernel(const float* __restrict__ s, const float* __restrict__ t,
                   uint32_t* __restrict__ Tout, uint32_t* __restrict__ Rout,
                   uint32_t* __restrict__ eqCntG, uint32_t* __restrict__ eqIdxG) {
    const int g = blockIdx.x, i = threadIdx.x;
    __shared__ float    torig[NNODES];
    __shared__ uint32_t skey[NNODES];
    __shared__ uint16_t sidx[NNODES];
    __shared__ float    tvs[NNODES];     // t values in key-ascending order
    __shared__ uint32_t wsum[16];
    __shared__ uint32_t sLo, sHi, sDir, sEqCnt;
    __shared__ uint32_t sEqList[EQCAP];

    const float tv_i = t[g * NNODES + i];
    torig[i] = tv_i;
    skey[i]  = fkey(tv_i);
    sidx[i]  = (uint16_t)i;
    if (i == 0) { sLo = 0u; sHi = 0xFFFFFFFFu; sEqCnt = 0u; }

    // ---- bitonic sort (keys + payload indices) -- R5 verbatim ----
    for (int k = 2; k <= NNODES; k <<= 1) {
        for (int j = k >> 1; j > 0; j >>= 1) {
            __syncthreads();
            int partner = i ^ j;
            if (partner > i) {
                bool asc = ((i & k) == 0);
                uint32_t a = skey[i], b = skey[partner];
                if ((a > b) == asc) {
                    skey[i] = b; skey[partner] = a;
                    uint16_t ia = sidx[i]; sidx[i] = sidx[partner]; sidx[partner] = ia;
                }
            }
        }
    }
    __syncthreads();
    tvs[i] = torig[sidx[i]];

    const float sv = s[g * NNODES + i];
    const bool sneg = (__float_as_uint(sv) >> 31) != 0;
    const uint32_t kdiag = fkey(sv * tv_i);   // diagonal element (excluded)
    __syncthreads();

    // boundary search within [lo_,hi_): for s>=+0 rows, (key>cand) true on
    // suffix starting at b; for s<0 rows, prefix ending at b. b monotone in cand.
    auto srchRange = [&](uint32_t cand, int lo_, int hi_) -> int {
        while (lo_ < hi_) {
            int mid = (lo_ + hi_) >> 1;
            bool pred = fkey(sv * tvs[mid]) > cand;
            bool goLeft = sneg ? !pred : pred;
            if (goLeft) hi_ = mid; else lo_ = mid + 1;
        }
        return lo_;
    };

    int rlo = 0, rhi = NNODES;       // per-row interval covering b(c), c in [sLo,sHi]
    uint32_t cntHi = 0u;             // thread 0 only: cnt_gt(sHi), exact at init

    // ---- binary search in key space: minimal T with cnt_gt(T) < K ----
    for (int it = 0; it < 33; ++it) {
        const uint32_t lo = sLo, hi = sHi;       // uniform (read after barrier)
        const uint32_t mid = lo + ((hi - lo) >> 1);
        const int b = srchRange(mid, rlo, rhi);
        uint32_t c = sneg ? (uint32_t)b : (uint32_t)(NNODES - b);
        if (kdiag > mid) c--;                    // exclude diagonal if it qualified
        uint32_t r = c;
        for (int off = 32; off; off >>= 1) r += __shfl_down(r, off);
        if ((i & 63) == 0) wsum[i >> 6] = r;
        __syncthreads();
        if (i == 0 && lo < hi) {
            uint32_t tot = 0;
            for (int w = 0; w < 16; ++w) tot += wsum[w];
            if (tot < TOPK) { sHi = mid; sDir = 0u; cntHi = tot; }  // go left
            else            { sLo = mid + 1; sDir = 1u; }           // go right
        }
        __syncthreads();
        if (lo < hi) {
            if (sDir == 0u) { if (!sneg) rhi = b; else rlo = b; }
            else            { if (!sneg) rlo = b; else rhi = b; }
        }
    }
    const uint32_t T = sLo;                      // sLo==sHi; cnt_gt(T)==cntHi
    if (i == 0) { Tout[g] = T; Rout[g] = TOPK - cntHi; }

    // ---- collect ties (key == T), diagonal excluded -- R5 verbatim ----
    auto bound = [&](bool ge) -> int {
        int lo_ = 0, hi_ = NNODES;
        while (lo_ < hi_) {
            int mid = (lo_ + hi_) >> 1;
            uint32_t k = fkey(sv * tvs[mid]);
            bool pred = ge ? (k >= T) : (k > T);
            bool goLeft = sneg ? !pred : pred;
            if (goLeft) hi_ = mid; else lo_ = mid + 1;
        }
        return lo_;
    };
    int e0, e1;
    if (!sneg) { e0 = bound(true);  e1 = bound(false); }   // equals = [ge, gt)
    else       { e0 = bound(false); e1 = bound(true);  }   // equals = [gt, ge)
    for (int p = e0; p < e1; ++p) {
        uint32_t j = sidx[p];
        if ((int)j == i) continue;
        uint32_t slot = atomicAdd(&sEqCnt, 1u);
        if (slot < EQCAP) sEqList[slot] = (uint32_t)(i * NNODES) + j;
    }
    __syncthreads();
    uint32_t E = sEqCnt; if (E > EQCAP) E = EQCAP;
    if (i == 0) eqCntG[g] = E;
    for (uint32_t p = i; p < E; p += NNODES) eqIdxG[g * EQCAP + p] = sEqList[p];
}

// ---------------------------------------------------------------------------
// Fill-shaped output writer with inline tie resolution. 2048 blocks x 256
// threads, grid-strided over all 33.55M float4s (64 iters/thread) -- same
// launch shape as the ~6.7 TB/s fill kernel. out = 1 iff (key>T && j!=i)
// or (key==T && j!=i && rank_among_ties < R); rank via scan of the tiny
// per-graph tie list (cold path). E >= R guaranteed (cnt_ge(T) >= K).
// ---------------------------------------------------------------------------
__global__ __launch_bounds__(256)
void write_kernel(const float* __restrict__ s, const float* __restrict__ t,
                  const uint32_t* __restrict__ Tin, const uint32_t* __restrict__ Rin,
                  const uint32_t* __restrict__ eqCntG, const uint32_t* __restrict__ eqIdxG,
                  float* __restrict__ out) {
    const uint32_t stride = gridDim.x * blockDim.x;          // float4 units
    const uint32_t total  = (uint32_t)NGRAPH * NNODES * (NNODES / 4);
    for (uint32_t f4 = blockIdx.x * blockDim.x + threadIdx.x; f4 < total; f4 += stride) {
        const uint32_t g  = f4 >> 18;            // 2^18 float4s per graph
        const uint32_t r  = f4 & 0x3FFFFu;
        const uint32_t i  = r >> 8;              // row
        const uint32_t c4 = r & 255u;            // float4 column
        const uint32_t j0 = c4 << 2;
        const uint32_t T  = Tin[g];
        const float sv = s[(g << 10) + i];
        const vfloat4 tv = ((const vfloat4*)t)[(g << 8) + c4];
        const uint32_t k0 = fkey(sv * tv.x), k1 = fkey(sv * tv.y);
        const uint32_t k2 = fkey(sv * tv.z), k3 = fkey(sv * tv.w);
        vfloat4 o;
        o.x = (k0 > T && (j0 + 0) != i) ? 1.0f : 0.0f;
        o.y = (k1 > T && (j0 + 1) != i) ? 1.0f : 0.0f;
        o.z = (k2 > T && (j0 + 2) != i) ? 1.0f : 0.0f;
        o.w = (k3 > T && (j0 + 3) != i) ? 1.0f : 0.0f;
        if (k0 == T || k1 == T || k2 == T || k3 == T) {       // cold path
            uint32_t E = eqCntG[g]; if (E > EQCAP) E = EQCAP;
            const uint32_t R = Rin[g];
            const uint32_t* eq = eqIdxG + (size_t)g * EQCAP;
            const uint32_t kk[4] = {k0, k1, k2, k3};
            #pragma unroll
            for (int q = 0; q < 4; ++q) {
                const uint32_t j = j0 + q;
                if (kk[q] == T && j != i) {
                    const uint32_t f = i * NNODES + j;
                    uint32_t rank = 0;
                    for (uint32_t e = 0; e < E; ++e) rank += (eq[e] < f) ? 1u : 0u;
                    if (rank < R) ((float*)&o)[q] = 1.0f;
                }
            }
        }
        ((vfloat4*)out)[f4] = o;
    }
}

extern "C" void kernel_launch(void* const* d_in, const int* in_sizes, int n_in,
                              void* d_out, int out_size, void* d_ws, size_t ws_size,
                              hipStream_t stream) {
    // inputs: x (unused), emb_s [G,N,1], emb_t [G,1,N] -- all float32
    const float* s = (const float*)d_in[1];
    const float* t = (const float*)d_in[2];
    float* out = (float*)d_out;

    char* ws = (char*)d_ws;
    uint32_t* Tbuf  = (uint32_t*)ws; ws += (size_t)NGRAPH * 4;
    uint32_t* Rbuf  = (uint32_t*)ws; ws += (size_t)NGRAPH * 4;
    uint32_t* eqCnt = (uint32_t*)ws; ws += (size_t)NGRAPH * 4;
    uint32_t* eqIdx = (uint32_t*)ws; ws += (size_t)NGRAPH * EQCAP * 4;

    select_kernel<<<NGRAPH, NNODES, 0, stream>>>(s, t, Tbuf, Rbuf, eqCnt, eqIdx);
    write_kernel<<<2048, 256, 0, stream>>>(s, t, Tbuf, Rbuf, eqCnt, eqIdx, out);
}

// Round 11
// 137.220 us; speedup vs baseline: 1.1898x; 1.1898x over previous
//
#include <hip/hip_runtime.h>
#include <stdint.h>

#define NNODES 1024
#define NGRAPH 128
#define TOPK   16384
#define EQCAP  4096

typedef float vfloat4 __attribute__((ext_vector_type(4)));

// Order-preserving monotone map fp32 -> u32 (larger float => larger key).
__device__ __forceinline__ uint32_t fkey(float x) {
    uint32_t u = __float_as_uint(x);
    return (u & 0x80000000u) ? ~u : (u | 0x80000000u);
}
// Exact bit-level inverse of fkey (validated R6/R9).
__device__ __forceinline__ float inv_fkey(uint32_t k) {
    uint32_t u = (k & 0x80000000u) ? (k & 0x7FFFFFFFu) : ~k;
    return __uint_as_float(u);
}

// ---------------------------------------------------------------------------
// Fused selection kernel, one 1024-thread block per graph. R5-validated
// structure with pure work-stripping:
//  - sort operates on ONE u64 LDS array packed (key<<16)|idx: halves the
//    DS ops per compare-exchange and deletes the separate key/idx/torig
//    arrays and the post-sort gather.
//  - 33-iter key-space binary search with per-row interval tracking
//    (R5 verbatim); thread 0 tracks cntHi = cnt_gt(hi) (validated R9/R10)
//    so no final exact-count pass.
//  - collect ties (key == T, diag excluded) into LDS, dump to global.
// Product s_i*t_j is monotone in t_j for fixed s_i (IEEE multiply); sign of
// s_i picks suffix/prefix direction. All comparisons on exact product keys.
// ---------------------------------------------------------------------------
__global__ __launch_bounds__(NNODES)
void select_kernel(const float* __restrict__ s, const float* __restrict__ t,
                   uint32_t* __restrict__ Tout, uint32_t* __restrict__ Rout,
                   uint32_t* __restrict__ eqCntG, uint32_t* __restrict__ eqIdxG) {
    const int g = blockIdx.x, i = threadIdx.x;
    __shared__ uint64_t spk[NNODES];     // packed (key<<16)|idx, sorted ascending
    __shared__ float    tvs[NNODES];     // t values in key-ascending order
    __shared__ uint32_t wsum[16];
    __shared__ uint32_t sLo, sHi, sDir, sEqCnt;
    __shared__ uint32_t sEqList[EQCAP];

    const float tv_i = t[g * NNODES + i];
    spk[i] = ((uint64_t)fkey(tv_i) << 16) | (uint32_t)i;
    if (i == 0) { sLo = 0u; sHi = 0xFFFFFFFFu; sEqCnt = 0u; }

    // ---- bitonic sort on packed u64 (R5 structure, half the DS ops) ----
    for (int k = 2; k <= NNODES; k <<= 1) {
        for (int j = k >> 1; j > 0; j >>= 1) {
            __syncthreads();
            int partner = i ^ j;
            if (partner > i) {
                bool asc = ((i & k) == 0);
                uint64_t a = spk[i], b = spk[partner];
                if ((a > b) == asc) { spk[i] = b; spk[partner] = a; }
            }
        }
    }
    __syncthreads();
    tvs[i] = inv_fkey((uint32_t)(spk[i] >> 16));

    const float sv = s[g * NNODES + i];
    const bool sneg = (__float_as_uint(sv) >> 31) != 0;
    const uint32_t kdiag = fkey(sv * tv_i);   // diagonal element (excluded)
    __syncthreads();

    // boundary search within [lo_,hi_): for s>=+0 rows, (key>cand) true on
    // suffix starting at b; for s<0 rows, prefix ending at b. b monotone in cand.
    auto srchRange = [&](uint32_t cand, int lo_, int hi_) -> int {
        while (lo_ < hi_) {
            int mid = (lo_ + hi_) >> 1;
            bool pred = fkey(sv * tvs[mid]) > cand;
            bool goLeft = sneg ? !pred : pred;
            if (goLeft) hi_ = mid; else lo_ = mid + 1;
        }
        return lo_;
    };

    int rlo = 0, rhi = NNODES;       // per-row interval covering b(c), c in [sLo,sHi]
    uint32_t cntHi = 0u;             // thread 0 only: cnt_gt(sHi), exact at init

    // ---- binary search in key space: minimal T with cnt_gt(T) < K (R5 loop) ----
    for (int it = 0; it < 33; ++it) {
        const uint32_t lo = sLo, hi = sHi;       // uniform (read after barrier)
        const uint32_t mid = lo + ((hi - lo) >> 1);
        const int b = srchRange(mid, rlo, rhi);
        uint32_t c = sneg ? (uint32_t)b : (uint32_t)(NNODES - b);
        if (kdiag > mid) c--;                    // exclude diagonal if it qualified
        uint32_t r = c;
        for (int off = 32; off; off >>= 1) r += __shfl_down(r, off);
        if ((i & 63) == 0) wsum[i >> 6] = r;
        __syncthreads();
        if (i == 0 && lo < hi) {
            uint32_t tot = 0;
            for (int w = 0; w < 16; ++w) tot += wsum[w];
            if (tot < TOPK) { sHi = mid; sDir = 0u; cntHi = tot; }  // go left
            else            { sLo = mid + 1; sDir = 1u; }           // go right
        }
        __syncthreads();
        if (lo < hi) {
            if (sDir == 0u) { if (!sneg) rhi = b; else rlo = b; }
            else            { if (!sneg) rlo = b; else rhi = b; }
        }
    }
    const uint32_t T = sLo;                      // sLo==sHi; cnt_gt(T)==cntHi
    if (i == 0) { Tout[g] = T; Rout[g] = TOPK - cntHi; }

    // ---- collect ties (key == T), diagonal excluded (R5 verbatim) ----
    auto bound = [&](bool ge) -> int {
        int lo_ = 0, hi_ = NNODES;
        while (lo_ < hi_) {
            int mid = (lo_ + hi_) >> 1;
            uint32_t k = fkey(sv * tvs[mid]);
            bool pred = ge ? (k >= T) : (k > T);
            bool goLeft = sneg ? !pred : pred;
            if (goLeft) hi_ = mid; else lo_ = mid + 1;
        }
        return lo_;
    };
    int e0, e1;
    if (!sneg) { e0 = bound(true);  e1 = bound(false); }   // equals = [ge, gt)
    else       { e0 = bound(false); e1 = bound(true);  }   // equals = [gt, ge)
    for (int p = e0; p < e1; ++p) {
        uint32_t j = (uint32_t)(spk[p] & 0xFFFFu);         // original column idx
        if ((int)j == i) continue;
        uint32_t slot = atomicAdd(&sEqCnt, 1u);
        if (slot < EQCAP) sEqList[slot] = (uint32_t)(i * NNODES) + j;
    }
    __syncthreads();
    uint32_t E = sEqCnt; if (E > EQCAP) E = EQCAP;
    if (i == 0) eqCntG[g] = E;
    for (uint32_t p = i; p < E; p += NNODES) eqIdxG[g * EQCAP + p] = sEqList[p];
}

// ---------------------------------------------------------------------------
// Output write, R5-validated shape (one block per output row, one float4
// store per thread -- empirically the fastest write shape: R5 141.8 beats
// 8-row/block 148.2 and grid-strided 163.3), with the tie resolution folded
// into a cold path (R10-validated logic): out = 1 iff (key>T && j!=i) or
// (key==T && j!=i && rank_among_ties < R). E >= R guaranteed.
// ---------------------------------------------------------------------------
__global__ __launch_bounds__(256)
void write_kernel(const float* __restrict__ s, const float* __restrict__ t,
                  const uint32_t* __restrict__ Tin, const uint32_t* __restrict__ Rin,
                  const uint32_t* __restrict__ eqCntG, const uint32_t* __restrict__ eqIdxG,
                  float* __restrict__ out) {
    const int b = blockIdx.x;           // g*1024 + i
    const int g = b >> 10, i = b & 1023;
    const uint32_t T = Tin[g];
    const float sv = s[(size_t)g * NNODES + i];
    const vfloat4 tv = ((const vfloat4*)(t + (size_t)g * NNODES))[threadIdx.x];
    const int j0 = threadIdx.x * 4;
    const uint32_t k0 = fkey(sv * tv.x), k1 = fkey(sv * tv.y);
    const uint32_t k2 = fkey(sv * tv.z), k3 = fkey(sv * tv.w);
    vfloat4 o;
    o.x = (k0 > T && (j0 + 0) != i) ? 1.0f : 0.0f;
    o.y = (k1 > T && (j0 + 1) != i) ? 1.0f : 0.0f;
    o.z = (k2 > T && (j0 + 2) != i) ? 1.0f : 0.0f;
    o.w = (k3 > T && (j0 + 3) != i) ? 1.0f : 0.0f;
    if (k0 == T || k1 == T || k2 == T || k3 == T) {          // cold path: ties
        uint32_t E = eqCntG[g]; if (E > EQCAP) E = EQCAP;
        const uint32_t R = Rin[g];
        const uint32_t* eq = eqIdxG + (size_t)g * EQCAP;
        const uint32_t kk[4] = {k0, k1, k2, k3};
        #pragma unroll
        for (int q = 0; q < 4; ++q) {
            const uint32_t j = j0 + q;
            if (kk[q] == T && (int)j != i) {
                const uint32_t f = (uint32_t)i * NNODES + j;
                uint32_t rank = 0;
                for (uint32_t e2 = 0; e2 < E; ++e2) rank += (eq[e2] < f) ? 1u : 0u;
                if (rank < R) ((float*)&o)[q] = 1.0f;
            }
        }
    }
    ((vfloat4*)(out + (size_t)g * NNODES * NNODES + (size_t)i * NNODES))[threadIdx.x] = o;
}

extern "C" void kernel_launch(void* const* d_in, const int* in_sizes, int n_in,
                              void* d_out, int out_size, void* d_ws, size_t ws_size,
                              hipStream_t stream) {
    // inputs: x (unused), emb_s [G,N,1], emb_t [G,1,N] -- all float32
    const float* s = (const float*)d_in[1];
    const float* t = (const float*)d_in[2];
    float* out = (float*)d_out;

    char* ws = (char*)d_ws;
    uint32_t* Tbuf  = (uint32_t*)ws; ws += (size_t)NGRAPH * 4;
    uint32_t* Rbuf  = (uint32_t*)ws; ws += (size_t)NGRAPH * 4;
    uint32_t* eqCnt = (uint32_t*)ws; ws += (size_t)NGRAPH * 4;
    uint32_t* eqIdx = (uint32_t*)ws; ws += (size_t)NGRAPH * EQCAP * 4;

    select_kernel<<<NGRAPH, NNODES, 0, stream>>>(s, t, Tbuf, Rbuf, eqCnt, eqIdx);
    write_kernel<<<NGRAPH * NNODES, 256, 0, stream>>>(s, t, Tbuf, Rbuf, eqCnt, eqIdx, out);
}

// Round 13
// 136.461 us; speedup vs baseline: 1.1965x; 1.0056x over previous
//
#include <hip/hip_runtime.h>
#include <stdint.h>

#define NNODES 1024
#define NGRAPH 128
#define TOPK   16384
#define EQCAP  4096

typedef float vfloat4 __attribute__((ext_vector_type(4)));

// Order-preserving monotone map fp32 -> u32 (larger float => larger key).
__device__ __forceinline__ uint32_t fkey(float x) {
    uint32_t u = __float_as_uint(x);
    return (u & 0x80000000u) ? ~u : (u | 0x80000000u);
}
// Exact bit-level inverse of fkey (validated R6/R9/R11).
__device__ __forceinline__ float inv_fkey(uint32_t k) {
    uint32_t u = (k & 0x80000000u) ? (k & 0x7FFFFFFFu) : ~k;
    return __uint_as_float(u);
}
// Compiler-only fence for wave-synchronous LDS (no HW cost). Valid ONLY when
// both the last writer and the reader of every address are in the same wave
// (DS ops within a wave execute in order).
__device__ __forceinline__ void wavefence() {
    __builtin_amdgcn_wave_barrier();
    asm volatile("" ::: "memory");
}

// ---------------------------------------------------------------------------
// Fused selection kernel, one 1024-thread block per graph. R11 structure.
//  - bitonic sort on packed u64 (key<<16)|idx, in-place in LDS. Barrier rule
//    (R12 bug fix): the lower thread writes BOTH pair slots, so a j>=64 step
//    writes cross-wave; the FOLLOWING step reads that data. Barrier needed
//    iff j>=64 (cross-wave read) OR previous step was cross-wave
//    (j==32 && k>128's descent). 14 barriers vs R11's 55.
//  - seeded search range: ub = max product key (cnt_gt(ub)=0, keeps cntHi
//    invariant exact); lb = min over rows of the row's 17TH-largest product
//    key (top-17 minus possible diagonal gives >=16 non-diag/row -> union
//    >= K elements >= lb -> T >= lb). Search loop breaks at lo==hi.
//  - key-space binary search with per-row interval tracking (R5/R11
//    verbatim); thread 0 tracks cntHi so no final count pass.
//  - collect ties (key == T, diag excluded) into LDS, dump to global.
// Product s_i*t_j is monotone in t_j for fixed s_i (IEEE multiply); sign of
// s_i picks suffix/prefix direction. All comparisons on exact product keys.
// ---------------------------------------------------------------------------
__global__ __launch_bounds__(NNODES)
void select_kernel(const float* __restrict__ s, const float* __restrict__ t,
                   uint32_t* __restrict__ Tout, uint32_t* __restrict__ Rout,
                   uint32_t* __restrict__ eqCntG, uint32_t* __restrict__ eqIdxG) {
    const int g = blockIdx.x, i = threadIdx.x;
    __shared__ uint64_t spk[NNODES];     // packed (key<<16)|idx, sorted ascending
    __shared__ float    tvs[NNODES];     // t values in key-ascending order
    __shared__ uint32_t wsum[16], wsum2[16];
    __shared__ uint32_t sLo, sHi, sDir, sEqCnt;
    __shared__ uint32_t sEqList[EQCAP];

    const float tv_i = t[g * NNODES + i];
    spk[i] = ((uint64_t)fkey(tv_i) << 16) | (uint32_t)i;
    if (i == 0) sEqCnt = 0u;

    // ---- bitonic sort on packed u64; barrier iff this step reads data a
    //      DIFFERENT wave wrote last step (see header) ----
    for (int k = 2; k <= NNODES; k <<= 1) {
        for (int j = k >> 1; j > 0; j >>= 1) {
            if ((j >= 64) || (j == 32 && k > 64)) __syncthreads();
            else                                  wavefence();
            int partner = i ^ j;
            if (partner > i) {
                bool asc = ((i & k) == 0);
                uint64_t a = spk[i], b = spk[partner];
                if ((a > b) == asc) { spk[i] = b; spk[partner] = a; }
            }
        }
    }
    __syncthreads();
    tvs[i] = inv_fkey((uint32_t)(spk[i] >> 16));

    const float sv = s[g * NNODES + i];
    const bool sneg = (__float_as_uint(sv) >> 31) != 0;
    const uint32_t kdiag = fkey(sv * tv_i);   // diagonal element (excluded)
    __syncthreads();                          // tvs visible to all

    // ---- seed [lb, ub]: one extra reduce round ----
    {
        uint32_t m = fkey(sv * tvs[sneg ? 0 : (NNODES - 1)]);    // row max key
        uint32_t n = fkey(sv * tvs[sneg ? 16 : (NNODES - 17)]);  // row 17th-largest key
        for (int off = 32; off; off >>= 1) {
            uint32_t mm = __shfl_down(m, off); if (mm > m) m = mm;
            uint32_t nn = __shfl_down(n, off); if (nn < n) n = nn;
        }
        if ((i & 63) == 0) { wsum[i >> 6] = m; wsum2[i >> 6] = n; }
        __syncthreads();
        if (i == 0) {
            uint32_t ub = 0u, lb = 0xFFFFFFFFu;
            for (int w = 0; w < 16; ++w) {
                if (wsum[w]  > ub) ub = wsum[w];
                if (wsum2[w] < lb) lb = wsum2[w];
            }
            sLo = lb; sHi = ub;
        }
        __syncthreads();
    }

    // boundary search within [lo_,hi_): for s>=+0 rows, (key>cand) true on
    // suffix starting at b; for s<0 rows, prefix ending at b. b monotone in cand.
    auto srchRange = [&](uint32_t cand, int lo_, int hi_) -> int {
        while (lo_ < hi_) {
            int mid = (lo_ + hi_) >> 1;
            bool pred = fkey(sv * tvs[mid]) > cand;
            bool goLeft = sneg ? !pred : pred;
            if (goLeft) hi_ = mid; else lo_ = mid + 1;
        }
        return lo_;
    };

    int rlo = 0, rhi = NNODES;       // per-row interval covering b(c), c in [sLo,sHi]
    uint32_t cntHi = 0u;             // thread 0 only: cnt_gt(sHi); exact (sHi=ub: 0)

    // ---- binary search: minimal T in [sLo,sHi] with cnt_gt(T) < K (R5 loop) ----
    for (int it = 0; it < 33; ++it) {
        const uint32_t lo = sLo, hi = sHi;       // uniform (read after barrier)
        if (lo >= hi) break;                     // uniform early exit
        const uint32_t mid = lo + ((hi - lo) >> 1);
        const int b = srchRange(mid, rlo, rhi);
        uint32_t c = sneg ? (uint32_t)b : (uint32_t)(NNODES - b);
        if (kdiag > mid) c--;                    // exclude diagonal if it qualified
        uint32_t r = c;
        for (int off = 32; off; off >>= 1) r += __shfl_down(r, off);
        if ((i & 63) == 0) wsum[i >> 6] = r;
        __syncthreads();
        if (i == 0) {
            uint32_t tot = 0;
            for (int w = 0; w < 16; ++w) tot += wsum[w];
            if (tot < TOPK) { sHi = mid; sDir = 0u; cntHi = tot; }  // go left
            else            { sLo = mid + 1; sDir = 1u; }           // go right
        }
        __syncthreads();
        if (sDir == 0u) { if (!sneg) rhi = b; else rlo = b; }
        else            { if (!sneg) rlo = b; else rhi = b; }
    }
    const uint32_t T = sLo;                      // sLo==sHi; cnt_gt(T)==cntHi
    if (i == 0) { Tout[g] = T; Rout[g] = TOPK - cntHi; }

    // ---- collect ties (key == T), diagonal excluded (R11 verbatim) ----
    auto bound = [&](bool ge) -> int {
        int lo_ = 0, hi_ = NNODES;
        while (lo_ < hi_) {
            int mid = (lo_ + hi_) >> 1;
            uint32_t k = fkey(sv * tvs[mid]);
            bool pred = ge ? (k >= T) : (k > T);
            bool goLeft = sneg ? !pred : pred;
            if (goLeft) hi_ = mid; else lo_ = mid + 1;
        }
        return lo_;
    };
    int e0, e1;
    if (!sneg) { e0 = bound(true);  e1 = bound(false); }   // equals = [ge, gt)
    else       { e0 = bound(false); e1 = bound(true);  }   // equals = [gt, ge)
    for (int p = e0; p < e1; ++p) {
        uint32_t j = (uint32_t)(spk[p] & 0xFFFFu);         // original column idx
        if ((int)j == i) continue;
        uint32_t slot = atomicAdd(&sEqCnt, 1u);
        if (slot < EQCAP) sEqList[slot] = (uint32_t)(i * NNODES) + j;
    }
    __syncthreads();
    uint32_t E = sEqCnt; if (E > EQCAP) E = EQCAP;
    if (i == 0) eqCntG[g] = E;
    for (uint32_t p = i; p < E; p += NNODES) eqIdxG[g * EQCAP + p] = sEqList[p];
}

// ---------------------------------------------------------------------------
// Output write, R5/R11-validated shape (one block per output row, one float4
// store per thread -- empirically fastest: beats 8-row/block and
// grid-strided), tie resolution folded into a cold path (R10/R11-validated).
// out = 1 iff (key>T && j!=i) or (key==T && j!=i && rank_among_ties < R).
// ---------------------------------------------------------------------------
__global__ __launch_bounds__(256)
void write_kernel(const float* __restrict__ s, const float* __restrict__ t,
                  const uint32_t* __restrict__ Tin, const uint32_t* __restrict__ Rin,
                  const uint32_t* __restrict__ eqCntG, const uint32_t* __restrict__ eqIdxG,
                  float* __restrict__ out) {
    const int b = blockIdx.x;           // g*1024 + i
    const int g = b >> 10, i = b & 1023;
    const uint32_t T = Tin[g];
    const float sv = s[(size_t)g * NNODES + i];
    const vfloat4 tv = ((const vfloat4*)(t + (size_t)g * NNODES))[threadIdx.x];
    const int j0 = threadIdx.x * 4;
    const uint32_t k0 = fkey(sv * tv.x), k1 = fkey(sv * tv.y);
    const uint32_t k2 = fkey(sv * tv.z), k3 = fkey(sv * tv.w);
    vfloat4 o;
    o.x = (k0 > T && (j0 + 0) != i) ? 1.0f : 0.0f;
    o.y = (k1 > T && (j0 + 1) != i) ? 1.0f : 0.0f;
    o.z = (k2 > T && (j0 + 2) != i) ? 1.0f : 0.0f;
    o.w = (k3 > T && (j0 + 3) != i) ? 1.0f : 0.0f;
    if (k0 == T || k1 == T || k2 == T || k3 == T) {          // cold path: ties
        uint32_t E = eqCntG[g]; if (E > EQCAP) E = EQCAP;
        const uint32_t R = Rin[g];
        const uint32_t* eq = eqIdxG + (size_t)g * EQCAP;
        const uint32_t kk[4] = {k0, k1, k2, k3};
        #pragma unroll
        for (int q = 0; q < 4; ++q) {
            const uint32_t j = j0 + q;
            if (kk[q] == T && (int)j != i) {
                const uint32_t f = (uint32_t)i * NNODES + j;
                uint32_t rank = 0;
                for (uint32_t e2 = 0; e2 < E; ++e2) rank += (eq[e2] < f) ? 1u : 0u;
                if (rank < R) ((float*)&o)[q] = 1.0f;
            }
        }
    }
    ((vfloat4*)(out + (size_t)g * NNODES * NNODES + (size_t)i * NNODES))[threadIdx.x] = o;
}

extern "C" void kernel_launch(void* const* d_in, const int* in_sizes, int n_in,
                              void* d_out, int out_size, void* d_ws, size_t ws_size,
                              hipStream_t stream) {
    // inputs: x (unused), emb_s [G,N,1], emb_t [G,1,N] -- all float32
    const float* s = (const float*)d_in[1];
    const float* t = (const float*)d_in[2];
    float* out = (float*)d_out;

    char* ws = (char*)d_ws;
    uint32_t* Tbuf  = (uint32_t*)ws; ws += (size_t)NGRAPH * 4;
    uint32_t* Rbuf  = (uint32_t*)ws; ws += (size_t)NGRAPH * 4;
    uint32_t* eqCnt = (uint32_t*)ws; ws += (size_t)NGRAPH * 4;
    uint32_t* eqIdx = (uint32_t*)ws; ws += (size_t)NGRAPH * EQCAP * 4;

    select_kernel<<<NGRAPH, NNODES, 0, stream>>>(s, t, Tbuf, Rbuf, eqCnt, eqIdx);
    write_kernel<<<NGRAPH * NNODES, 256, 0, stream>>>(s, t, Tbuf, Rbuf, eqCnt, eqIdx, out);
}

// Round 14
// 129.924 us; speedup vs baseline: 1.2567x; 1.0503x over previous
//
#include <hip/hip_runtime.h>
#include <stdint.h>

#define NNODES 1024
#define NGRAPH 128
#define TOPK   16384
#define EQCAP  4096

typedef float vfloat4 __attribute__((ext_vector_type(4)));

// Order-preserving monotone map fp32 -> u32 (larger float => larger key).
__device__ __forceinline__ uint32_t fkey(float x) {
    uint32_t u = __float_as_uint(x);
    return (u & 0x80000000u) ? ~u : (u | 0x80000000u);
}
// Exact bit-level inverse of fkey (validated R6/R9/R11).
__device__ __forceinline__ float inv_fkey(uint32_t k) {
    uint32_t u = (k & 0x80000000u) ? (k & 0x7FFFFFFFu) : ~k;
    return __uint_as_float(u);
}
// Compiler-only fence for wave-synchronous LDS (no HW cost).
__device__ __forceinline__ void wavefence() {
    __builtin_amdgcn_wave_barrier();
    asm volatile("" ::: "memory");
}
// Wave64 sum on the VALU pipe via DPP (zero DS-pipe traffic, unlike __shfl
// which lowers to ds_bpermute). Canonical gfx9 sequence; lane 63 holds the
// full sum afterwards. bound_ctrl=true -> out-of-range lanes read 0 (sum id).
__device__ __forceinline__ uint32_t wave_sum_dpp(uint32_t v) {
    int x = (int)v;
    x += __builtin_amdgcn_update_dpp(0, x, 0x111, 0xF, 0xF, true);  // row_shr:1
    x += __builtin_amdgcn_update_dpp(0, x, 0x112, 0xF, 0xF, true);  // row_shr:2
    x += __builtin_amdgcn_update_dpp(0, x, 0x114, 0xF, 0xF, true);  // row_shr:4
    x += __builtin_amdgcn_update_dpp(0, x, 0x118, 0xF, 0xF, true);  // row_shr:8
    x += __builtin_amdgcn_update_dpp(0, x, 0x142, 0xF, 0xF, true);  // row_bcast:15
    x += __builtin_amdgcn_update_dpp(0, x, 0x143, 0xF, 0xF, true);  // row_bcast:31
    return (uint32_t)x;
}

// ---------------------------------------------------------------------------
// Fused selection kernel, one 1024-thread block per graph. R13 structure;
// the ONLY change this round: the per-round block reduce uses a DPP (VALU)
// wave sum instead of __shfl_down (ds_bpermute) -- removes 6 DS ops per
// thread per search round from the DS pipe, which R4/R7/R13 established as
// the binding resource.
//  - bitonic sort on packed u64 (key<<16)|idx; barrier iff the step reads
//    data another wave wrote last step (j>=64 || (j==32 && k>64)) -- R13.
//  - seeded search range [lb, ub] (R13): ub = max product key; lb = min over
//    rows of the row's 17th-largest product key.
//  - key-space binary search, per-row interval tracking (R5); thread 0
//    tracks cntHi = cnt_gt(hi), exact from seed (cnt_gt(ub) = 0).
//  - collect ties (key == T, diag excluded) into LDS, dump to global.
// ---------------------------------------------------------------------------
__global__ __launch_bounds__(NNODES)
void select_kernel(const float* __restrict__ s, const float* __restrict__ t,
                   uint32_t* __restrict__ Tout, uint32_t* __restrict__ Rout,
                   uint32_t* __restrict__ eqCntG, uint32_t* __restrict__ eqIdxG) {
    const int g = blockIdx.x, i = threadIdx.x;
    __shared__ uint64_t spk[NNODES];     // packed (key<<16)|idx, sorted ascending
    __shared__ float    tvs[NNODES];     // t values in key-ascending order
    __shared__ uint32_t wsum[16], wsum2[16];
    __shared__ uint32_t sLo, sHi, sDir, sEqCnt;
    __shared__ uint32_t sEqList[EQCAP];

    const float tv_i = t[g * NNODES + i];
    spk[i] = ((uint64_t)fkey(tv_i) << 16) | (uint32_t)i;
    if (i == 0) sEqCnt = 0u;

    // ---- bitonic sort on packed u64 (R13 barrier rule) ----
    for (int k = 2; k <= NNODES; k <<= 1) {
        for (int j = k >> 1; j > 0; j >>= 1) {
            if ((j >= 64) || (j == 32 && k > 64)) __syncthreads();
            else                                  wavefence();
            int partner = i ^ j;
            if (partner > i) {
                bool asc = ((i & k) == 0);
                uint64_t a = spk[i], b = spk[partner];
                if ((a > b) == asc) { spk[i] = b; spk[partner] = a; }
            }
        }
    }
    __syncthreads();
    tvs[i] = inv_fkey((uint32_t)(spk[i] >> 16));

    const float sv = s[g * NNODES + i];
    const bool sneg = (__float_as_uint(sv) >> 31) != 0;
    const uint32_t kdiag = fkey(sv * tv_i);   // diagonal element (excluded)
    __syncthreads();                          // tvs visible to all

    // ---- seed [lb, ub] (R13 verbatim) ----
    {
        uint32_t m = fkey(sv * tvs[sneg ? 0 : (NNODES - 1)]);    // row max key
        uint32_t n = fkey(sv * tvs[sneg ? 16 : (NNODES - 17)]);  // row 17th-largest key
        for (int off = 32; off; off >>= 1) {
            uint32_t mm = __shfl_down(m, off); if (mm > m) m = mm;
            uint32_t nn = __shfl_down(n, off); if (nn < n) n = nn;
        }
        if ((i & 63) == 0) { wsum[i >> 6] = m; wsum2[i >> 6] = n; }
        __syncthreads();
        if (i == 0) {
            uint32_t ub = 0u, lb = 0xFFFFFFFFu;
            for (int w = 0; w < 16; ++w) {
                if (wsum[w]  > ub) ub = wsum[w];
                if (wsum2[w] < lb) lb = wsum2[w];
            }
            sLo = lb; sHi = ub;
        }
        __syncthreads();
    }

    // boundary search within [lo_,hi_): for s>=+0 rows, (key>cand) true on
    // suffix starting at b; for s<0 rows, prefix ending at b. b monotone in cand.
    auto srchRange = [&](uint32_t cand, int lo_, int hi_) -> int {
        while (lo_ < hi_) {
            int mid = (lo_ + hi_) >> 1;
            bool pred = fkey(sv * tvs[mid]) > cand;
            bool goLeft = sneg ? !pred : pred;
            if (goLeft) hi_ = mid; else lo_ = mid + 1;
        }
        return lo_;
    };

    int rlo = 0, rhi = NNODES;       // per-row interval covering b(c), c in [sLo,sHi]
    uint32_t cntHi = 0u;             // thread 0 only: cnt_gt(sHi); exact (sHi=ub: 0)

    // ---- binary search: minimal T in [sLo,sHi] with cnt_gt(T) < K ----
    for (int it = 0; it < 33; ++it) {
        const uint32_t lo = sLo, hi = sHi;       // uniform (read after barrier)
        if (lo >= hi) break;                     // uniform early exit
        const uint32_t mid = lo + ((hi - lo) >> 1);
        const int b = srchRange(mid, rlo, rhi);
        uint32_t c = sneg ? (uint32_t)b : (uint32_t)(NNODES - b);
        if (kdiag > mid) c--;                    // exclude diagonal if it qualified
        uint32_t r = wave_sum_dpp(c);            // VALU-pipe reduce; lane 63 valid
        if ((i & 63) == 63) wsum[i >> 6] = r;
        __syncthreads();
        if (i == 0) {
            uint32_t tot = 0;
            for (int w = 0; w < 16; ++w) tot += wsum[w];
            if (tot < TOPK) { sHi = mid; sDir = 0u; cntHi = tot; }  // go left
            else            { sLo = mid + 1; sDir = 1u; }           // go right
        }
        __syncthreads();
        if (sDir == 0u) { if (!sneg) rhi = b; else rlo = b; }
        else            { if (!sneg) rlo = b; else rhi = b; }
    }
    const uint32_t T = sLo;                      // sLo==sHi; cnt_gt(T)==cntHi
    if (i == 0) { Tout[g] = T; Rout[g] = TOPK - cntHi; }

    // ---- collect ties (key == T), diagonal excluded (R11 verbatim) ----
    auto bound = [&](bool ge) -> int {
        int lo_ = 0, hi_ = NNODES;
        while (lo_ < hi_) {
            int mid = (lo_ + hi_) >> 1;
            uint32_t k = fkey(sv * tvs[mid]);
            bool pred = ge ? (k >= T) : (k > T);
            bool goLeft = sneg ? !pred : pred;
            if (goLeft) hi_ = mid; else lo_ = mid + 1;
        }
        return lo_;
    };
    int e0, e1;
    if (!sneg) { e0 = bound(true);  e1 = bound(false); }   // equals = [ge, gt)
    else       { e0 = bound(false); e1 = bound(true);  }   // equals = [gt, ge)
    for (int p = e0; p < e1; ++p) {
        uint32_t j = (uint32_t)(spk[p] & 0xFFFFu);         // original column idx
        if ((int)j == i) continue;
        uint32_t slot = atomicAdd(&sEqCnt, 1u);
        if (slot < EQCAP) sEqList[slot] = (uint32_t)(i * NNODES) + j;
    }
    __syncthreads();
    uint32_t E = sEqCnt; if (E > EQCAP) E = EQCAP;
    if (i == 0) eqCntG[g] = E;
    for (uint32_t p = i; p < E; p += NNODES) eqIdxG[g * EQCAP + p] = sEqList[p];
}

// ---------------------------------------------------------------------------
// Output write, R5/R11-validated shape (one block per output row, one float4
// store per thread), tie resolution folded into a cold path (R10/R11).
// out = 1 iff (key>T && j!=i) or (key==T && j!=i && rank_among_ties < R).
// ---------------------------------------------------------------------------
__global__ __launch_bounds__(256)
void write_kernel(const float* __restrict__ s, const float* __restrict__ t,
                  const uint32_t* __restrict__ Tin, const uint32_t* __restrict__ Rin,
                  const uint32_t* __restrict__ eqCntG, const uint32_t* __restrict__ eqIdxG,
                  float* __restrict__ out) {
    const int b = blockIdx.x;           // g*1024 + i
    const int g = b >> 10, i = b & 1023;
    const uint32_t T = Tin[g];
    const float sv = s[(size_t)g * NNODES + i];
    const vfloat4 tv = ((const vfloat4*)(t + (size_t)g * NNODES))[threadIdx.x];
    const int j0 = threadIdx.x * 4;
    const uint32_t k0 = fkey(sv * tv.x), k1 = fkey(sv * tv.y);
    const uint32_t k2 = fkey(sv * tv.z), k3 = fkey(sv * tv.w);
    vfloat4 o;
    o.x = (k0 > T && (j0 + 0) != i) ? 1.0f : 0.0f;
    o.y = (k1 > T && (j0 + 1) != i) ? 1.0f : 0.0f;
    o.z = (k2 > T && (j0 + 2) != i) ? 1.0f : 0.0f;
    o.w = (k3 > T && (j0 + 3) != i) ? 1.0f : 0.0f;
    if (k0 == T || k1 == T || k2 == T || k3 == T) {          // cold path: ties
        uint32_t E = eqCntG[g]; if (E > EQCAP) E = EQCAP;
        const uint32_t R = Rin[g];
        const uint32_t* eq = eqIdxG + (size_t)g * EQCAP;
        const uint32_t kk[4] = {k0, k1, k2, k3};
        #pragma unroll
        for (int q = 0; q < 4; ++q) {
            const uint32_t j = j0 + q;
            if (kk[q] == T && (int)j != i) {
                const uint32_t f = (uint32_t)i * NNODES + j;
                uint32_t rank = 0;
                for (uint32_t e2 = 0; e2 < E; ++e2) rank += (eq[e2] < f) ? 1u : 0u;
                if (rank < R) ((float*)&o)[q] = 1.0f;
            }
        }
    }
    ((vfloat4*)(out + (size_t)g * NNODES * NNODES + (size_t)i * NNODES))[threadIdx.x] = o;
}

extern "C" void kernel_launch(void* const* d_in, const int* in_sizes, int n_in,
                              void* d_out, int out_size, void* d_ws, size_t ws_size,
                              hipStream_t stream) {
    // inputs: x (unused), emb_s [G,N,1], emb_t [G,1,N] -- all float32
    const float* s = (const float*)d_in[1];
    const float* t = (const float*)d_in[2];
    float* out = (float*)d_out;

    char* ws = (char*)d_ws;
    uint32_t* Tbuf  = (uint32_t*)ws; ws += (size_t)NGRAPH * 4;
    uint32_t* Rbuf  = (uint32_t*)ws; ws += (size_t)NGRAPH * 4;
    uint32_t* eqCnt = (uint32_t*)ws; ws += (size_t)NGRAPH * 4;
    uint32_t* eqIdx = (uint32_t*)ws; ws += (size_t)NGRAPH * EQCAP * 4;

    select_kernel<<<NGRAPH, NNODES, 0, stream>>>(s, t, Tbuf, Rbuf, eqCnt, eqIdx);
    write_kernel<<<NGRAPH * NNODES, 256, 0, stream>>>(s, t, Tbuf, Rbuf, eqCnt, eqIdx, out);
}